// Round 4
// baseline (141.830 us; speedup 1.0000x reference)
//
#include <hip/hip_runtime.h>

#define M_TOT 4096
#define B_TOT 8
#define N_TOT 512
#define FD    128
#define BD    128
#define BVD   6
#define H     64
#define H2    32
#define MAX_TILES 264   // 4096/16 + 8 possible ragged tails

// ---------------------------------------------------------------------------
// K_pre: fused precompute. Roles by blockIdx:
//   [0,256)    f_mh[m][h]      = Wf @ f_pre_in[m] + bf
//   [256,512)  b_feat[b][h][n] = Wb @ b_pre_in[b,:,n] + bb
//   [512,768)  bv_T[b][n][h]   = Wbv @ bv_in[b,:,n] + bbv   (transposed)
//   768        plan: ragged batch-uniform tile table (<=264 tiles of <=16 rows)
// ---------------------------------------------------------------------------
__device__ __forceinline__ int lb_dev(const int* __restrict__ arr, int n, int v) {
    int lo = 0, hi = n;
    while (lo < hi) { int mid = (lo + hi) >> 1; if (arr[mid] < v) lo = mid + 1; else hi = mid; }
    return lo;
}

__global__ __launch_bounds__(256) void k_pre(const float* __restrict__ f_pre_in,
                                             const int*   __restrict__ batch,
                                             const float* __restrict__ b_pre_in,
                                             const float* __restrict__ bv_in,
                                             const float* __restrict__ Wf,
                                             const float* __restrict__ bf,
                                             const float* __restrict__ Wb,
                                             const float* __restrict__ bb,
                                             const float* __restrict__ Wbv,
                                             const float* __restrict__ bbv,
                                             float* __restrict__ f_mh,
                                             float* __restrict__ b_feat,
                                             float* __restrict__ bv_T,
                                             int4*  __restrict__ table) {
    __shared__ float fpre[16 * 132];
    __shared__ float WfT[128 * 68];
    __shared__ float ws2[2 * 132];
    const int t = threadIdx.x;
    const int blk = blockIdx.x;

    if (blk < 256) {
        // ---- f role: 16 m x 64 h per block ----
        const int m0 = blk * 16;
        for (int i = t; i < 16 * FD; i += 256)
            fpre[(i >> 7) * 132 + (i & 127)] = f_pre_in[(size_t)m0 * FD + i];
        for (int i = t; i < H * FD; i += 256)
            WfT[(i & 127) * 68 + (i >> 7)] = Wf[i];
        __syncthreads();
        const int mi = t >> 4;
        const int h4 = (t & 15) * 4;
        float a0 = bf[h4], a1 = bf[h4 + 1], a2 = bf[h4 + 2], a3 = bf[h4 + 3];
#pragma unroll 4
        for (int d4 = 0; d4 < 32; ++d4) {
            const float4 fp = *(const float4*)&fpre[mi * 132 + d4 * 4];
            const float* fpp = &fp.x;
#pragma unroll
            for (int i = 0; i < 4; ++i) {
                const float4 wv = *(const float4*)&WfT[(d4 * 4 + i) * 68 + h4];
                const float f = fpp[i];
                a0 += f * wv.x; a1 += f * wv.y; a2 += f * wv.z; a3 += f * wv.w;
            }
        }
        *(float4*)&f_mh[(size_t)(m0 + mi) * H + h4] = make_float4(a0, a1, a2, a3);
    } else if (blk < 512) {
        // ---- b_feat role ----
        const int idx = blk - 256;
        const int b  = idx >> 5;
        const int h0 = (idx & 31) * 2;
        ws2[(t >> 7) * 132 + (t & 127)] = Wb[(h0 + (t >> 7)) * BD + (t & 127)];
        __syncthreads();
        const int hi = t >> 7;
        const int n4 = (t & 127) * 4;
        const float bias = bb[h0 + hi];
        float a0 = bias, a1 = bias, a2 = bias, a3 = bias;
        const float* src = b_pre_in + (size_t)b * BD * N_TOT + n4;
        const float* wp = &ws2[hi * 132];
#pragma unroll 8
        for (int d = 0; d < BD; ++d) {
            const float wv = wp[d];
            const float4 v = *(const float4*)(src + (size_t)d * N_TOT);
            a0 += wv * v.x; a1 += wv * v.y; a2 += wv * v.z; a3 += wv * v.w;
        }
        *(float4*)&b_feat[((size_t)b * H + h0 + hi) * N_TOT + n4] = make_float4(a0, a1, a2, a3);
    } else if (blk < 768) {
        // ---- bv_T role (transposed output) ----
        const int idx = blk - 512;
        const int b  = idx >> 5;
        const int n0 = (idx & 31) * 16;
        const int h  = t & 63;
        const int nq = t >> 6;
        float wreg[BVD];
#pragma unroll
        for (int c = 0; c < BVD; ++c) wreg[c] = Wbv[h * BVD + c];
        const float bias = bbv[h];
        const float* src = bv_in + (size_t)b * BVD * N_TOT;
#pragma unroll
        for (int j = 0; j < 4; ++j) {
            const int n = n0 + nq * 4 + j;
            float acc = bias;
#pragma unroll
            for (int c = 0; c < BVD; ++c) acc += wreg[c] * src[c * N_TOT + n];
            bv_T[((size_t)b * N_TOT + n) * H + h] = acc;
        }
    } else {
        // ---- plan role: ragged batch-uniform 16-row tiles ----
        int starts[9];
#pragma unroll
        for (int b = 0; b <= 8; ++b) starts[b] = lb_dev(batch, M_TOT, b);
        int pre[9]; pre[0] = 0;
#pragma unroll
        for (int b = 0; b < 8; ++b) pre[b + 1] = pre[b] + (starts[b + 1] - starts[b] + 15) / 16;
        const int total = pre[8];
        for (int idx = t; idx < MAX_TILES; idx += 256) {
            int4 e = make_int4(0, 0, 0, 0);
            if (idx < total) {
                int b = 0;
                while (pre[b + 1] <= idx) ++b;
                const int r0 = starts[b] + (idx - pre[b]) * 16;
                e.x = b; e.y = r0; e.z = min(16, starts[b + 1] - r0);
            }
            table[idx] = e;
        }
    }
}

// ---------------------------------------------------------------------------
// K_main v4: grid = 4 n-quarters x MAX_TILES, 512 threads.
// Register-tiled scores (4r x 4n per thread, h-quarter split over lane bits
// 0-1, DPP-shuffle reduce) and PV (4r x 4h per thread, b128-only LDS reads,
// in-register w transpose). All hot LDS traffic is ds_read_b128.
// ---------------------------------------------------------------------------
__global__ __launch_bounds__(512, 4) void k_main(const float* __restrict__ f_mh,
                                                 const float* __restrict__ b_feat,
                                                 const float* __restrict__ bv_T,
                                                 const int4*  __restrict__ table,
                                                 float* __restrict__ pOut,
                                                 float* __restrict__ pSum) {
    __shared__ float sbuf[128 * 72];    // bF phase: [64 h][132] (8448 <= 9216); bv phase: [128 n][72]
    __shared__ float wTe[128 * 20 + 4]; // [n][r] stride 20
    __shared__ float wTg[128 * 20 + 4];
    __shared__ float fT[64 * 20];       // [h][r] stride 20
    __shared__ float rowsum[16][2];

    const int t = threadIdx.x;
    const int q    = blockIdx.x & 3;
    const int tile = blockIdx.x >> 2;
    const int4 te = table[tile];
    const int b = te.x, m0 = te.y, nr = te.z;
    if (nr == 0) return;
    const int nb = q * 128;

    if (t < 32) rowsum[t >> 1][t & 1] = 0.f;
    // stage fT [h][r] (coalesced reads over h)
    for (int i = t; i < 16 * H; i += 512) {
        const int h = i & 63, r = i >> 6;
        fT[h * 20 + r] = f_mh[(size_t)(m0 + min(r, nr - 1)) * H + h];
    }
    // stage bF chunk [64 h][132]
    {
        const float* src = b_feat + (size_t)b * H * N_TOT + nb;
        for (int i = t; i < 2048; i += 512) {
            const int h = i >> 5, n4 = (i & 31) * 4;
            *(float4*)&sbuf[h * 132 + n4] = *(const float4*)&src[(size_t)h * N_TOT + n4];
        }
    }
    __syncthreads();

    const int hq = t & 3;
    const int nq = (t >> 2) & 31;
    const int rg = t >> 7;          // wave-uniform
    const int n4 = nq * 4;
    const int r4 = rg * 4;

    // ---- scores: 4r x 4n per thread, h interleaved h = hh*4 + hq ----
    float se[4][4], sg[4][4];       // [jn][r]
#pragma unroll
    for (int j = 0; j < 4; ++j)
#pragma unroll
        for (int r = 0; r < 4; ++r) { se[j][r] = 0.f; sg[j][r] = 0.f; }
#pragma unroll
    for (int hh = 0; hh < 8; ++hh) {
        const int h = hh * 4 + hq;                         // euc: h in [0,32)
        const float4 fr = *(const float4*)&fT[h * 20 + r4];
        const float4 bn = *(const float4*)&sbuf[h * 132 + n4];
        const float* frp = &fr.x; const float* bnp = &bn.x;
#pragma unroll
        for (int j = 0; j < 4; ++j)
#pragma unroll
            for (int r = 0; r < 4; ++r) se[j][r] += bnp[j] * frp[r];
    }
#pragma unroll
    for (int hh = 0; hh < 8; ++hh) {
        const int h = 32 + hh * 4 + hq;                    // geo: h in [32,64)
        const float4 fr = *(const float4*)&fT[h * 20 + r4];
        const float4 bn = *(const float4*)&sbuf[h * 132 + n4];
        const float* frp = &fr.x; const float* bnp = &bn.x;
#pragma unroll
        for (int j = 0; j < 4; ++j)
#pragma unroll
            for (int r = 0; r < 4; ++r) sg[j][r] += bnp[j] * frp[r];
    }
    // reduce partial h over the 4 hq lanes (bits 0-1)
#pragma unroll
    for (int j = 0; j < 4; ++j)
#pragma unroll
        for (int r = 0; r < 4; ++r) {
            float v = se[j][r]; v += __shfl_xor(v, 1); v += __shfl_xor(v, 2); se[j][r] = v;
            float u = sg[j][r]; u += __shfl_xor(u, 1); u += __shfl_xor(u, 2); sg[j][r] = u;
        }
    // exp (no max-subtract: |s/8| bounded ~1.5) + per-row partial sums
    float we_[4][4], wg_[4][4];
    float pe[4] = {0.f, 0.f, 0.f, 0.f}, pg[4] = {0.f, 0.f, 0.f, 0.f};
#pragma unroll
    for (int j = 0; j < 4; ++j)
#pragma unroll
        for (int r = 0; r < 4; ++r) {
            we_[j][r] = __expf(se[j][r] * 0.125f); pe[r] += we_[j][r];
            wg_[j][r] = __expf(sg[j][r] * 0.125f); pg[r] += wg_[j][r];
        }
    // reduce row sums over nq (lane bits 2-5), atomic per wave
#pragma unroll
    for (int r = 0; r < 4; ++r) {
        float v = pe[r];
        v += __shfl_xor(v, 4); v += __shfl_xor(v, 8); v += __shfl_xor(v, 16); v += __shfl_xor(v, 32);
        pe[r] = v;
        float u = pg[r];
        u += __shfl_xor(u, 4); u += __shfl_xor(u, 8); u += __shfl_xor(u, 16); u += __shfl_xor(u, 32);
        pg[r] = u;
    }
    if ((t & 63) == 0) {
#pragma unroll
        for (int r = 0; r < 4; ++r) {
            atomicAdd(&rowsum[r4 + r][0], pe[r]);
            atomicAdd(&rowsum[r4 + r][1], pg[r]);
        }
    }
    // in-register transpose: write w as [n][r] (hq==0 lanes only)
    if (hq == 0) {
#pragma unroll
        for (int j = 0; j < 4; ++j) {
            *(float4*)&wTe[(n4 + j) * 20 + r4] = make_float4(we_[j][0], we_[j][1], we_[j][2], we_[j][3]);
            *(float4*)&wTg[(n4 + j) * 20 + r4] = make_float4(wg_[j][0], wg_[j][1], wg_[j][2], wg_[j][3]);
        }
    }
    __syncthreads();

    // ---- stage bv chunk into sbuf as [128 n][72 h-padded] ----
    {
        const float* src = bv_T + ((size_t)b * N_TOT + nb) * H;
        for (int i = t; i < 2048; i += 512) {
            const int n = i >> 4, h4s = (i & 15) * 4;
            *(float4*)&sbuf[n * 72 + h4s] = *(const float4*)&src[(size_t)n * H + h4s];
        }
    }
    __syncthreads();

    // rowsum final -> pSum
    if (t < 32) {
        const int r = t >> 1, eg = t & 1;
        if (r < nr) pSum[((size_t)q * M_TOT + m0 + r) * 2 + eg] = rowsum[r][eg];
    }

    // ---- PV: 4r x 4h per thread; per n: 3x b128 -> 32 FMA ----
    const int ns = t & 7;
    const int h4 = ((t >> 3) & 15) * 4;
    float aE[4][4], aG[4][4];   // [r][c]
#pragma unroll
    for (int r = 0; r < 4; ++r)
#pragma unroll
        for (int c = 0; c < 4; ++c) { aE[r][c] = 0.f; aG[r][c] = 0.f; }
#pragma unroll
    for (int i = 0; i < 16; ++i) {
        const int n = ns + 8 * i;
        const float4 w4e = *(const float4*)&wTe[n * 20 + r4];
        const float4 w4g = *(const float4*)&wTg[n * 20 + r4];
        const float4 v4  = *(const float4*)&sbuf[n * 72 + h4];
        const float* wep = &w4e.x; const float* wgp = &w4g.x; const float* vp = &v4.x;
#pragma unroll
        for (int r = 0; r < 4; ++r)
#pragma unroll
            for (int c = 0; c < 4; ++c) {
                aE[r][c] += wep[r] * vp[c];
                aG[r][c] += wgp[r] * vp[c];
            }
    }
    // reduce over ns (lane bits 0-2)
#pragma unroll
    for (int r = 0; r < 4; ++r)
#pragma unroll
        for (int c = 0; c < 4; ++c) {
            float v = aE[r][c]; v += __shfl_xor(v, 1); v += __shfl_xor(v, 2); v += __shfl_xor(v, 4); aE[r][c] = v;
            float u = aG[r][c]; u += __shfl_xor(u, 1); u += __shfl_xor(u, 2); u += __shfl_xor(u, 4); aG[r][c] = u;
        }
    if (ns == 0) {
#pragma unroll
        for (int j = 0; j < 4; ++j) {
            if (r4 + j < nr) {
                float* dst = pOut + ((size_t)q * M_TOT + m0 + r4 + j) * 128;
                *(float4*)&dst[h4]      = make_float4(aE[j][0], aE[j][1], aE[j][2], aE[j][3]);
                *(float4*)&dst[64 + h4] = make_float4(aG[j][0], aG[j][1], aG[j][2], aG[j][3]);
            }
        }
    }
}

// ---------------------------------------------------------------------------
// K_merge: cat = (sum_q pOut) / (sum_q pSum); out = cat @ Wo^T + bo.
// ---------------------------------------------------------------------------
__global__ __launch_bounds__(256) void k_merge(const float* __restrict__ pOut,
                                               const float* __restrict__ pSum,
                                               const float* __restrict__ Wo,
                                               const float* __restrict__ bo,
                                               float* __restrict__ out) {
    __shared__ float WoT[128 * 68];   // [k][j]
    __shared__ float cat[16 * 132];
    __shared__ float rinv[16][2];
    const int t = threadIdx.x;
    const int m0 = blockIdx.x * 16;

    for (int i = t; i < H * 2 * H; i += 256)
        WoT[(i & 127) * 68 + (i >> 7)] = Wo[i];
    if (t < 32) {
        const int r = t >> 1, eg = t & 1;
        float s = 0.f;
#pragma unroll
        for (int qq = 0; qq < 4; ++qq) s += pSum[((size_t)qq * M_TOT + m0 + r) * 2 + eg];
        rinv[r][eg] = 1.0f / s;
    }
    __syncthreads();

    for (int i = t; i < 512; i += 256) {
        const int r = i >> 5, k4 = (i & 31) * 4;
        float4 s = make_float4(0.f, 0.f, 0.f, 0.f);
#pragma unroll
        for (int qq = 0; qq < 4; ++qq) {
            const float4 v = *(const float4*)&pOut[(((size_t)qq * M_TOT + m0 + r) * 128) + k4];
            s.x += v.x; s.y += v.y; s.z += v.z; s.w += v.w;
        }
        const float inv = rinv[r][k4 >= 64];
        *(float4*)&cat[r * 132 + k4] = make_float4(s.x * inv, s.y * inv, s.z * inv, s.w * inv);
    }
    __syncthreads();

    const int mi = t >> 4;
    const int j4 = (t & 15) * 4;
    float a0 = bo[j4], a1 = bo[j4 + 1], a2 = bo[j4 + 2], a3 = bo[j4 + 3];
#pragma unroll 4
    for (int k4s = 0; k4s < 32; ++k4s) {
        const float4 c4 = *(const float4*)&cat[mi * 132 + 4 * k4s];
        const float* cp = &c4.x;
#pragma unroll
        for (int i = 0; i < 4; ++i) {
            const float4 wv = *(const float4*)&WoT[(4 * k4s + i) * 68 + j4];
            const float c = cp[i];
            a0 += c * wv.x; a1 += c * wv.y; a2 += c * wv.z; a3 += c * wv.w;
        }
    }
    *(float4*)&out[(size_t)(m0 + mi) * H + j4] = make_float4(a0, a1, a2, a3);
}

extern "C" void kernel_launch(void* const* d_in, const int* in_sizes, int n_in,
                              void* d_out, int out_size, void* d_ws, size_t ws_size,
                              hipStream_t stream) {
    const float* f_pre_in = (const float*)d_in[0];
    const int*   f_batch  = (const int*)  d_in[1];
    const float* b_pre_in = (const float*)d_in[2];
    const float* bv_in    = (const float*)d_in[3];
    const float* Wf       = (const float*)d_in[4];
    const float* bf       = (const float*)d_in[5];
    const float* Wb       = (const float*)d_in[6];
    const float* bb       = (const float*)d_in[7];
    const float* Wbv      = (const float*)d_in[8];
    const float* bbv      = (const float*)d_in[9];
    const float* Wo       = (const float*)d_in[10];
    const float* bo       = (const float*)d_in[11];
    float* out = (float*)d_out;

    float* f_mh   = (float*)d_ws;                               // 262144 f
    float* b_feat = f_mh + (size_t)M_TOT * H;                   // 262144 f
    float* bv_T   = b_feat + (size_t)B_TOT * H * N_TOT;         // 262144 f
    float* pOut   = bv_T + (size_t)B_TOT * N_TOT * H;           // 4*4096*128 f
    float* pSum   = pOut + (size_t)4 * M_TOT * 128;             // 4*4096*2 f
    int4*  table  = (int4*)(pSum + (size_t)4 * M_TOT * 2);      // 264 int4

    k_pre  <<<769, 256, 0, stream>>>(f_pre_in, f_batch, b_pre_in, bv_in,
                                     Wf, bf, Wb, bb, Wbv, bbv,
                                     f_mh, b_feat, bv_T, table);
    k_main <<<4 * MAX_TILES, 512, 0, stream>>>(f_mh, b_feat, bv_T, table, pOut, pSum);
    k_merge<<<256, 256, 0, stream>>>(pOut, pSum, Wo, bo, out);
}

// Round 5
// 109.293 us; speedup vs baseline: 1.2977x; 1.2977x over previous
//
#include <hip/hip_runtime.h>

#define M_TOT 4096
#define B_TOT 8
#define N_TOT 512
#define FD    128
#define BD    128
#define BVD   6
#define H     64
#define MAX_TILES 264   // 4096/16 + 8 ragged tails

typedef short short8 __attribute__((ext_vector_type(8)));   // 8 bf16 = 4 VGPRs (MFMA A/B frag)
typedef float floatx4 __attribute__((ext_vector_type(4)));  // MFMA C/D frag

__device__ __forceinline__ unsigned short f2bf(float x) {   // RNE float->bf16
    union { float f; unsigned int u; } v; v.f = x;
    return (unsigned short)((v.u + 0x7fffu + ((v.u >> 16) & 1u)) >> 16);
}
__device__ __forceinline__ float bf2f(unsigned short u) {
    union { unsigned int u32; float f; } v; v.u32 = ((unsigned int)u) << 16;
    return v.f;
}

__device__ __forceinline__ int lb_dev(const int* __restrict__ arr, int n, int v) {
    int lo = 0, hi = n;
    while (lo < hi) { int mid = (lo + hi) >> 1; if (arr[mid] < v) lo = mid + 1; else hi = mid; }
    return lo;
}

// ---------------------------------------------------------------------------
// K_pre: roles by blockIdx:
//   [0,256)    f_bf[m][h]      (bf16)  = Wf @ f_pre_in[m] + bf
//   [256,512)  bFT_bf[b][n][h] (bf16)  = (Wb @ b_pre_in[b,:,n] + bb) transposed
//   [512,768)  bv_bf[b][h][n]  (bf16)  = Wbv @ bv_in[b,:,n] + bbv
//   768        tile table + Wo_bf[j][k] (bf16)
// ---------------------------------------------------------------------------
__global__ __launch_bounds__(256) void k_pre(const float* __restrict__ f_pre_in,
                                             const int*   __restrict__ batch,
                                             const float* __restrict__ b_pre_in,
                                             const float* __restrict__ bv_in,
                                             const float* __restrict__ Wf,
                                             const float* __restrict__ bf,
                                             const float* __restrict__ Wb,
                                             const float* __restrict__ bb,
                                             const float* __restrict__ Wbv,
                                             const float* __restrict__ bbv,
                                             const float* __restrict__ Wo,
                                             unsigned short* __restrict__ f_bf,
                                             unsigned short* __restrict__ bFT_bf,
                                             unsigned short* __restrict__ bv_bf,
                                             unsigned short* __restrict__ Wo_bf,
                                             int4*  __restrict__ table) {
    __shared__ __align__(16) char sm[43264];
    const int t = threadIdx.x;
    const int blk = blockIdx.x;

    if (blk < 256) {
        // ---- f role: 16 m x 64 h per block ----
        float* fpre = (float*)sm;           // [16][132]
        float* WfT  = (float*)(sm + 8448);  // [128][68]
        const int m0 = blk * 16;
        for (int i = t; i < 16 * FD; i += 256)
            fpre[(i >> 7) * 132 + (i & 127)] = f_pre_in[(size_t)m0 * FD + i];
        for (int i = t; i < H * FD; i += 256)
            WfT[(i & 127) * 68 + (i >> 7)] = Wf[i];
        __syncthreads();
        const int mi = t >> 4;
        const int h4 = (t & 15) * 4;
        float a0 = bf[h4], a1 = bf[h4 + 1], a2 = bf[h4 + 2], a3 = bf[h4 + 3];
#pragma unroll 4
        for (int d4 = 0; d4 < 32; ++d4) {
            const float4 fp = *(const float4*)&fpre[mi * 132 + d4 * 4];
            const float* fpp = &fp.x;
#pragma unroll
            for (int i = 0; i < 4; ++i) {
                const float4 wv = *(const float4*)&WfT[(d4 * 4 + i) * 68 + h4];
                const float f = fpp[i];
                a0 += f * wv.x; a1 += f * wv.y; a2 += f * wv.z; a3 += f * wv.w;
            }
        }
        ushort4 o; o.x = f2bf(a0); o.y = f2bf(a1); o.z = f2bf(a2); o.w = f2bf(a3);
        *(ushort4*)&f_bf[(size_t)(m0 + mi) * H + h4] = o;
    } else if (blk < 512) {
        // ---- bFT role: block = (b, 16-n chunk); thread = (h, 4 n) ----
        float* Wb_l = (float*)sm;            // [64][129]
        float* bp   = (float*)(sm + 33024);  // [128][17]
        const int idx = blk - 256;
        const int b  = idx >> 5;
        const int n0 = (idx & 31) * 16;
        for (int i = t; i < H * BD; i += 256)
            Wb_l[(i >> 7) * 129 + (i & 127)] = Wb[i];
        for (int i = t; i < BD * 16; i += 256)
            bp[(i >> 4) * 17 + (i & 15)] =
                b_pre_in[(size_t)b * BD * N_TOT + (size_t)(i >> 4) * N_TOT + n0 + (i & 15)];
        __syncthreads();
        const int h  = t & 63;
        const int nl = t >> 6;
        const float bias = bb[h];
        float acc[4] = {bias, bias, bias, bias};
        const float* wr = &Wb_l[h * 129];
#pragma unroll 8
        for (int d = 0; d < BD; ++d) {
            const float w = wr[d];
            acc[0] += w * bp[d * 17 + nl];
            acc[1] += w * bp[d * 17 + nl + 4];
            acc[2] += w * bp[d * 17 + nl + 8];
            acc[3] += w * bp[d * 17 + nl + 12];
        }
#pragma unroll
        for (int j = 0; j < 4; ++j)
            bFT_bf[((size_t)b * N_TOT + n0 + nl + 4 * j) * H + h] = f2bf(acc[j]);
    } else if (blk < 768) {
        // ---- bv role: block = (b, 2 h); thread = 4 n ----
        const int idx = blk - 512;
        const int b  = idx >> 5;
        const int h  = (idx & 31) * 2 + (t >> 7);
        const int n4 = (t & 127) * 4;
        float w[BVD];
#pragma unroll
        for (int c = 0; c < BVD; ++c) w[c] = Wbv[h * BVD + c];
        const float bias = bbv[h];
        float a0 = bias, a1 = bias, a2 = bias, a3 = bias;
        const float* src = bv_in + (size_t)b * BVD * N_TOT + n4;
#pragma unroll
        for (int c = 0; c < BVD; ++c) {
            const float4 v = *(const float4*)(src + c * N_TOT);
            a0 += w[c] * v.x; a1 += w[c] * v.y; a2 += w[c] * v.z; a3 += w[c] * v.w;
        }
        ushort4 o; o.x = f2bf(a0); o.y = f2bf(a1); o.z = f2bf(a2); o.w = f2bf(a3);
        *(ushort4*)&bv_bf[((size_t)b * H + h) * N_TOT + n4] = o;
    } else {
        // ---- misc role: tile table + Wo bf16 ----
        int starts[9];
#pragma unroll
        for (int b = 0; b <= 8; ++b) starts[b] = lb_dev(batch, M_TOT, b);
        int pre[9]; pre[0] = 0;
#pragma unroll
        for (int b = 0; b < 8; ++b) pre[b + 1] = pre[b] + (starts[b + 1] - starts[b] + 15) / 16;
        const int total = pre[8];
        for (int idx = t; idx < MAX_TILES; idx += 256) {
            int4 e = make_int4(0, 0, 0, 0);
            if (idx < total) {
                int b = 0;
                while (pre[b + 1] <= idx) ++b;
                const int r0 = starts[b] + (idx - pre[b]) * 16;
                e.x = b; e.y = r0; e.z = min(16, starts[b + 1] - r0);
            }
            table[idx] = e;
        }
        for (int i = t; i < H * 2 * H; i += 256) Wo_bf[i] = f2bf(Wo[i]);
    }
}

// ---------------------------------------------------------------------------
// K_main (MFMA): one block (256 thr, 4 waves) per 16-row batch-uniform tile.
// Wave w owns n-quarter [128w,128w+128). Phases:
//  1) S^T = bF_chunk(16n x 32h) x f^T  via mfma_16x16x32_bf16 (K=32 = H/2).
//  2) exp (no max-subtract; |s/8| bounded), bf16-round, pack b64 -> W_lds[r][n];
//     rowsums via quad shuffles -> per-wave slots (no atomics).
//  3) PV: O_partial = W x bv^T, A-frags b128 from own-wave W_lds, B 16B global.
//  4) barrier; cross-wave reduce + normalize -> cat bf16.
//  5) barrier; out = cat @ Wo^T + bo via MFMA, direct store. No merge kernel.
// ---------------------------------------------------------------------------
__global__ __launch_bounds__(256) void k_main(const unsigned short* __restrict__ f_bf,
                                              const unsigned short* __restrict__ bFT_bf,
                                              const unsigned short* __restrict__ bv_bf,
                                              const unsigned short* __restrict__ Wo_bf,
                                              const float* __restrict__ bo,
                                              const int4*  __restrict__ table,
                                              float* __restrict__ out) {
    // per-wave region: W bf16 [2 eg][16 r][136 n] = 8704 B; later reused as
    // O-partials f32 [2 eg][64 h][16 r] = 8192 B (wave-local alias, program order).
    __shared__ __align__(16) char wreg[4][8704];
    __shared__ __align__(16) float rowsumP[4][2][16];
    __shared__ __align__(16) unsigned short cat_l[16 * 136];

    const int t = threadIdx.x;
    const int wave = t >> 6, l = t & 63, quad = l >> 4, s = l & 15;
    const int4 te = table[blockIdx.x];
    const int b = te.x, m0 = te.y, nr = te.z;
    if (nr == 0) return;

    unsigned short* Wl = (unsigned short*)&wreg[wave][0];
    const floatx4 zero = {0.f, 0.f, 0.f, 0.f};

    // ---- f B-frags (rows clamped for ragged tiles) ----
    const int rclamp = (s < nr) ? s : (nr - 1);
    const unsigned short* fptr = f_bf + (size_t)(m0 + rclamp) * H + quad * 8;
    const short8 fE = *(const short8*)(fptr);
    const short8 fG = *(const short8*)(fptr + 32);

    // ---- phase 1: scores S^T, 8 chunks of 16 n ----
    const unsigned short* bA = bFT_bf + ((size_t)b * N_TOT + wave * 128 + s) * H + quad * 8;
    floatx4 dE[8], dG[8];
#pragma unroll
    for (int c = 0; c < 8; ++c) {
        const short8 aE = *(const short8*)(bA + (size_t)c * 16 * H);
        const short8 aG = *(const short8*)(bA + (size_t)c * 16 * H + 32);
        dE[c] = __builtin_amdgcn_mfma_f32_16x16x32_bf16(aE, fE, zero, 0, 0, 0);
        dG[c] = __builtin_amdgcn_mfma_f32_16x16x32_bf16(aG, fG, zero, 0, 0, 0);
    }

    // ---- phase 2: exp, bf16 round, pack -> W_lds; rowsums ----
    float rsE = 0.f, rsG = 0.f;
#pragma unroll
    for (int c = 0; c < 8; ++c) {
        ushort4 pE, pG;
        unsigned short u;
        u = f2bf(__expf(dE[c][0] * 0.125f)); rsE += bf2f(u); pE.x = u;
        u = f2bf(__expf(dE[c][1] * 0.125f)); rsE += bf2f(u); pE.y = u;
        u = f2bf(__expf(dE[c][2] * 0.125f)); rsE += bf2f(u); pE.z = u;
        u = f2bf(__expf(dE[c][3] * 0.125f)); rsE += bf2f(u); pE.w = u;
        u = f2bf(__expf(dG[c][0] * 0.125f)); rsG += bf2f(u); pG.x = u;
        u = f2bf(__expf(dG[c][1] * 0.125f)); rsG += bf2f(u); pG.y = u;
        u = f2bf(__expf(dG[c][2] * 0.125f)); rsG += bf2f(u); pG.z = u;
        u = f2bf(__expf(dG[c][3] * 0.125f)); rsG += bf2f(u); pG.w = u;
        // lane holds rows n = c*16 + quad*4 + reg (consecutive regs), col r = s
        *(ushort4*)&Wl[s * 136 + c * 16 + quad * 4]        = pE;
        *(ushort4*)&Wl[2176 + s * 136 + c * 16 + quad * 4] = pG;
    }
    rsE += __shfl_xor(rsE, 16); rsE += __shfl_xor(rsE, 32);
    rsG += __shfl_xor(rsG, 16); rsG += __shfl_xor(rsG, 32);
    if (l < 16) { rowsumP[wave][0][s] = rsE; rowsumP[wave][1][s] = rsG; }

    // ---- phase 3: PV (A from own-wave W_lds; B 16B global; shared E/G B-frags) ----
    floatx4 oE[4] = {zero, zero, zero, zero};
    floatx4 oG[4] = {zero, zero, zero, zero};
#pragma unroll
    for (int kc = 0; kc < 4; ++kc) {
        const short8 aE = *(const short8*)&Wl[s * 136 + kc * 32 + quad * 8];
        const short8 aG = *(const short8*)&Wl[2176 + s * 136 + kc * 32 + quad * 8];
#pragma unroll
        for (int hc = 0; hc < 4; ++hc) {
            const short8 bvf = *(const short8*)(bv_bf +
                ((size_t)b * H + hc * 16 + s) * N_TOT + wave * 128 + kc * 32 + quad * 8);
            oE[hc] = __builtin_amdgcn_mfma_f32_16x16x32_bf16(aE, bvf, oE[hc], 0, 0, 0);
            oG[hc] = __builtin_amdgcn_mfma_f32_16x16x32_bf16(aG, bvf, oG[hc], 0, 0, 0);
        }
    }
    // write O partials into the (now consumed) W region: [eg][h][16 r] f32
    {
        float* Op = (float*)&wreg[wave][0];
#pragma unroll
        for (int hc = 0; hc < 4; ++hc) {
            *(floatx4*)&Op[(hc * 16 + s) * 16 + quad * 4]        = oE[hc];
            *(floatx4*)&Op[1024 + (hc * 16 + s) * 16 + quad * 4] = oG[hc];
        }
    }
    __syncthreads();

    // ---- phase 4: cross-wave reduce + normalize -> cat bf16 [16 r][136 k] ----
    {
        const int h  = t >> 2;
        const int r4 = (t & 3) * 4;
        floatx4 sE = zero, sG = zero, rE = zero, rG = zero;
#pragma unroll
        for (int w = 0; w < 4; ++w) {
            const float* opw = (const float*)&wreg[w][0];
            sE += *(const floatx4*)&opw[h * 16 + r4];
            sG += *(const floatx4*)&opw[1024 + h * 16 + r4];
            rE += *(const floatx4*)&rowsumP[w][0][r4];
            rG += *(const floatx4*)&rowsumP[w][1][r4];
        }
#pragma unroll
        for (int i = 0; i < 4; ++i) {
            cat_l[(r4 + i) * 136 + h]      = f2bf(sE[i] / rE[i]);
            cat_l[(r4 + i) * 136 + 64 + h] = f2bf(sG[i] / rG[i]);
        }
    }
    __syncthreads();

    // ---- phase 5: out = cat @ Wo^T + bo (wave w -> j in [16w,16w+16)) ----
    {
        floatx4 acc = zero;
#pragma unroll
        for (int kc = 0; kc < 4; ++kc) {
            const short8 aC = *(const short8*)&cat_l[s * 136 + kc * 32 + quad * 8];
            const short8 bW = *(const short8*)(Wo_bf + (size_t)(wave * 16 + s) * 128 + kc * 32 + quad * 8);
            acc = __builtin_amdgcn_mfma_f32_16x16x32_bf16(aC, bW, acc, 0, 0, 0);
        }
        const int j = wave * 16 + s;
        const float bj = bo[j];
#pragma unroll
        for (int reg = 0; reg < 4; ++reg) {
            const int r = quad * 4 + reg;
            if (r < nr) out[(size_t)(m0 + r) * H + j] = acc[reg] + bj;
        }
    }
}

extern "C" void kernel_launch(void* const* d_in, const int* in_sizes, int n_in,
                              void* d_out, int out_size, void* d_ws, size_t ws_size,
                              hipStream_t stream) {
    const float* f_pre_in = (const float*)d_in[0];
    const int*   f_batch  = (const int*)  d_in[1];
    const float* b_pre_in = (const float*)d_in[2];
    const float* bv_in    = (const float*)d_in[3];
    const float* Wf       = (const float*)d_in[4];
    const float* bf       = (const float*)d_in[5];
    const float* Wb       = (const float*)d_in[6];
    const float* bb       = (const float*)d_in[7];
    const float* Wbv      = (const float*)d_in[8];
    const float* bbv      = (const float*)d_in[9];
    const float* Wo       = (const float*)d_in[10];
    const float* bo       = (const float*)d_in[11];
    float* out = (float*)d_out;

    // ws layout (ushort elements, then table)
    unsigned short* f_bf   = (unsigned short*)d_ws;            // 4096*64
    unsigned short* bFT_bf = f_bf + (size_t)M_TOT * H;         // 8*512*64
    unsigned short* bv_bf  = bFT_bf + (size_t)B_TOT * N_TOT * H;
    unsigned short* Wo_bf  = bv_bf + (size_t)B_TOT * H * N_TOT;
    int4* table = (int4*)(Wo_bf + (size_t)H * 2 * H);          // byte offset % 16 == 0

    k_pre <<<769, 256, 0, stream>>>(f_pre_in, f_batch, b_pre_in, bv_in,
                                    Wf, bf, Wb, bb, Wbv, bbv, Wo,
                                    f_bf, bFT_bf, bv_bf, Wo_bf, table);
    k_main<<<MAX_TILES, 256, 0, stream>>>(f_bf, bFT_bf, bv_bf, Wo_bf, bo, table, out);
}